// Round 1
// baseline (50.943 us; speedup 1.0000x reference)
//
#include <hip/hip_runtime.h>
#include <math.h>

#define NUM_CLASSES 80
#define BB 16
#define AA 3
#define HH 85
#define WW 85
#define HW (HH*WW)
#define MM 50
#define CH (AA*(5+NUM_CLASSES))   // 255

__device__ __forceinline__ float sigmoidf_(float x){ return 1.0f/(1.0f+expf(-x)); }

__device__ __forceinline__ double bce_(float p, float t){
    float lp = logf(fmaxf(p, 1e-30f));
    float lq = logf(fmaxf(1.0f - p, 1e-30f));
    return -(double)(t*lp + (1.0f - t)*lq);
}

__device__ __forceinline__ float iou_cxcywh_(float ax,float ay,float aw,float ah,
                                             float bx,float by,float bw,float bh){
    float tlx = fmaxf(ax - aw*0.5f, bx - bw*0.5f);
    float tly = fmaxf(ay - ah*0.5f, by - bh*0.5f);
    float brx = fminf(ax + aw*0.5f, bx + bw*0.5f);
    float bry = fminf(ay + ah*0.5f, by + bh*0.5f);
    float area_a = aw*ah, area_b = bw*bh;
    float en = (tlx < brx && tly < bry) ? 1.0f : 0.0f;
    float ai = (brx - tlx)*(bry - tly)*en;
    return ai/(area_a + area_b - ai);
}

// K1: per-GT metadata + winner scatter (last GT index wins == lax.scan overwrite order)
__global__ void k_pergt(const float* __restrict__ targets,
                        const float* __restrict__ masked_anchors,
                        const float* __restrict__ ref_anchors,
                        const int* __restrict__ anchor_mask,
                        float* __restrict__ gt_box, float* __restrict__ gt_delta,
                        float* __restrict__ gt_scale, int4* __restrict__ gt_meta,
                        int* __restrict__ nobj, int* __restrict__ winner){
    int t = blockIdx.x*blockDim.x + threadIdx.x;
    if (t >= BB*MM) return;
    int b = t / MM, m = t % MM;
    int no = 0;
    for (int j = 0; j < MM; ++j){
        const float* r = targets + ((size_t)b*MM + j)*5;
        float s = r[0]+r[1]+r[2]+r[3]+r[4];
        no += (s > 0.0f) ? 1 : 0;
    }
    if (m == 0) nobj[b] = no;
    const float* g = targets + ((size_t)b*MM + m)*5;
    float gx = g[0]*(float)WW, gy = g[1]*(float)HH, gw = g[2]*(float)WW, gh = g[3]*(float)HH;
    int cls = (int)g[4];
    cls = min(max(cls, 0), NUM_CLASSES-1);
    bool valid = (m < no);
    int cx = (int)floorf(gx), cy = (int)floorf(gy);
    int cell = min(max(cy*WW + cx, 0), HW-1);
    float xg = (float)(cell % WW), yg = (float)(cell / WW);
    // argmax over 9 reference anchors at this cell (first max wins, like jnp.argmax)
    float best = -1e30f; int aidx = 0;
    for (int r = 0; r < 9; ++r){
        float off = (r % 3 == 0) ? 0.5f : 0.0f;   // ref_grid.at[:, 0::3, :2].add(0.5)
        float iou = iou_cxcywh_(xg+off, yg+off, ref_anchors[2*r], ref_anchors[2*r+1],
                                gx, gy, gw, gh);
        if (iou > best){ best = iou; aidx = r; }
    }
    bool dof = valid && (aidx == anchor_mask[0] || aidx == anchor_mask[1] || aidx == anchor_mask[2]);
    int a3 = aidx % 3;
    float mw = masked_anchors[2*a3], mh = masked_anchors[2*a3+1];
    gt_box[t*4+0] = gx; gt_box[t*4+1] = gy; gt_box[t*4+2] = gw; gt_box[t*4+3] = gh;
    gt_delta[t*4+0] = gx - xg; gt_delta[t*4+1] = gy - yg;
    gt_delta[t*4+2] = gw/mw;   gt_delta[t*4+3] = gh/mh;
    gt_scale[t] = sqrtf(2.0f - gw*gh/(float)WW/(float)HH);
    gt_meta[t] = make_int4(dof ? 1 : 0, cell, a3, cls);
    if (dof) atomicMax(&winner[((size_t)b*AA + a3)*HW + cell], m);
}

// K2: max IoU(pred_box, gt) per (b,a,hw) + n_pos count
__global__ void k_maxiou(const float* __restrict__ outputs,
                         const float* __restrict__ masked_anchors,
                         const float* __restrict__ gt_box,
                         const int* __restrict__ nobj,
                         float* __restrict__ max_iou, int* __restrict__ npos){
    int t = blockIdx.x*blockDim.x + threadIdx.x;
    if (t >= BB*AA*HW) return;
    int hw = t % HW; int ba = t / HW; int a = ba % AA; int b = ba / AA;
    int xg = hw % WW, yg = hw / WW;
    size_t base = ((size_t)b*CH + a*(5+NUM_CLASSES))*HW + hw;
    float bx = sigmoidf_(outputs[base])        + (float)xg;
    float by = sigmoidf_(outputs[base + HW])   + (float)yg;
    float bw = expf(outputs[base + 2*HW]) * masked_anchors[2*a];
    float bh = expf(outputs[base + 3*HW]) * masked_anchors[2*a+1];
    int no = nobj[b];
    float mv = -1.0f;
    const float* gb = gt_box + (size_t)b*MM*4;
    for (int m = 0; m < no; ++m){
        float iou = iou_cxcywh_(bx, by, bw, bh, gb[4*m], gb[4*m+1], gb[4*m+2], gb[4*m+3]);
        mv = fmaxf(mv, iou);
    }
    max_iou[t] = mv;
    if (mv > 0.7f) atomicAdd(&npos[b], 1);
}

// K3: loss reduction. Non-positive cells contribute only the conf BCE term.
__global__ void __launch_bounds__(256) k_loss(
        const float* __restrict__ outputs,
        const float* __restrict__ gt_delta,
        const float* __restrict__ gt_scale,
        const int4* __restrict__ gt_meta,
        const float* __restrict__ max_iou,
        const int* __restrict__ winner,
        const int* __restrict__ nobj,
        const int* __restrict__ npos,
        double* __restrict__ acc){
    int t = blockIdx.x*blockDim.x + threadIdx.x;
    double l = 0.0;
    if (t < BB*AA*HW){
        int hw = t % HW; int ba = t / HW; int a = ba % AA; int b = ba / AA;
        size_t base = ((size_t)b*CH + a*(5+NUM_CLASSES))*HW + hw;
        float mi = max_iou[t];
        int win = winner[t];
        float imask = 1.0f;
        if (npos[b] > 0 && mi >= 0.7f) imask = 0.0f;
        if (win >= 0) imask = 1.0f;
        if (nobj[b] == 0) imask = 0.0f;
        if (imask != 0.0f){
            float p = sigmoidf_(outputs[base + 4*HW]);
            float tt = (win >= 0) ? mi : 0.0f;
            l += bce_(p, tt);
        }
        if (win >= 0){
            int gi = b*MM + win;
            float dx = gt_delta[gi*4], dy = gt_delta[gi*4+1];
            float dw = gt_delta[gi*4+2], dh = gt_delta[gi*4+3];
            float s = gt_scale[gi];
            double w2 = (double)(s*s);
            float p0 = sigmoidf_(outputs[base]);
            float p1 = sigmoidf_(outputs[base + HW]);
            l += bce_(p0, dx)*w2 + bce_(p1, dy)*w2;
            float e2 = expf(outputs[base + 2*HW]);
            float e3 = expf(outputs[base + 3*HW]);
            float d2 = e2*s - dw*s, d3 = e3*s - dh*s;
            l += 0.5*((double)(d2*d2) + (double)(d3*d3));
            // class target bitmask: OR of one-hots over ALL matching do-GTs (scan semantics)
            unsigned long long cm0 = 0ull, cm1 = 0ull;
            const int4* gm = gt_meta + (size_t)b*MM;
            for (int m = 0; m < MM; ++m){
                int4 mmv = gm[m];
                if (mmv.x && mmv.y == hw && mmv.z == a){
                    int c = mmv.w;
                    if (c < 64) cm0 |= (1ull << c); else cm1 |= (1ull << (c-64));
                }
            }
            for (int c = 0; c < NUM_CLASSES; ++c){
                float p = sigmoidf_(outputs[base + (size_t)(5+c)*HW]);
                float tt = (((c < 64 ? (cm0 >> c) : (cm1 >> (c-64))) & 1ull) != 0ull) ? 1.0f : 0.0f;
                l += bce_(p, tt);
            }
        }
    }
    __shared__ double sred[256];
    int tid = threadIdx.x;
    sred[tid] = l;
    __syncthreads();
    for (int s = 128; s > 0; s >>= 1){
        if (tid < s) sred[tid] += sred[tid + s];
        __syncthreads();
    }
    if (tid == 0) atomicAdd(acc, sred[0]);
}

__global__ void k_final(const double* __restrict__ acc, float* __restrict__ out){
    out[0] = (float)acc[0];
}

extern "C" void kernel_launch(void* const* d_in, const int* in_sizes, int n_in,
                              void* d_out, int out_size, void* d_ws, size_t ws_size,
                              hipStream_t stream) {
    const float* outputs        = (const float*)d_in[0];
    const float* targets        = (const float*)d_in[1];
    const float* masked_anchors = (const float*)d_in[2];
    const float* ref_anchors    = (const float*)d_in[3];
    const int*   anchor_mask    = (const int*)d_in[4];

    char* ws = (char*)d_ws;
    // layout (all 16B-aligned offsets)
    double* acc      = (double*)(ws + 0);          // 8 B
    int*    npos     = (int*)(ws + 16);            // 64 B
    int*    nobj     = (int*)(ws + 80);            // 64 B
    float*  gt_box   = (float*)(ws + 144);         // 12800 B
    float*  gt_delta = (float*)(ws + 12944);       // 12800 B
    float*  gt_scale = (float*)(ws + 25744);       // 3200 B
    int4*   gt_meta  = (int4*)(ws + 28944);        // 12800 B
    int*    winner   = (int*)(ws + 41744);         // 1387200 B
    float*  max_iou  = (float*)(ws + 1428944);     // 1387200 B  (end: 2816144)

    hipMemsetAsync(ws, 0, 144, stream);                               // acc + npos (+nobj)
    hipMemsetAsync(winner, 0xFF, (size_t)BB*AA*HW*sizeof(int), stream); // winner = -1

    k_pergt<<<(BB*MM + 63)/64, 64, 0, stream>>>(targets, masked_anchors, ref_anchors,
                                                anchor_mask, gt_box, gt_delta, gt_scale,
                                                gt_meta, nobj, winner);
    int nthreads = BB*AA*HW;
    int nblk = (nthreads + 255)/256;
    k_maxiou<<<nblk, 256, 0, stream>>>(outputs, masked_anchors, gt_box, nobj, max_iou, npos);
    k_loss<<<nblk, 256, 0, stream>>>(outputs, gt_delta, gt_scale, gt_meta, max_iou,
                                     winner, nobj, npos, acc);
    k_final<<<1, 1, 0, stream>>>(acc, (float*)d_out);
}

// Round 2
// 35.714 us; speedup vs baseline: 1.4264x; 1.4264x over previous
//
#include <hip/hip_runtime.h>
#include <math.h>

#define NUM_CLASSES 80
#define BB 16
#define AA 3
#define HH 85
#define WW 85
#define HW (HH*WW)
#define MM 50
#define CH (AA*(5+NUM_CLASSES))   // 255

__device__ __forceinline__ float sigmoidf_(float x){ return 1.0f/(1.0f+expf(-x)); }

__device__ __forceinline__ double bce_(float p, float t){
    float lp = logf(fmaxf(p, 1e-30f));
    float lq = logf(fmaxf(1.0f - p, 1e-30f));
    return -(double)(t*lp + (1.0f - t)*lq);
}

__device__ __forceinline__ float iou_cxcywh_(float ax,float ay,float aw,float ah,
                                             float bx,float by,float bw,float bh){
    float tlx = fmaxf(ax - aw*0.5f, bx - bw*0.5f);
    float tly = fmaxf(ay - ah*0.5f, by - bh*0.5f);
    float brx = fminf(ax + aw*0.5f, bx + bw*0.5f);
    float bry = fminf(ay + ah*0.5f, by + bh*0.5f);
    float area_a = aw*ah, area_b = bw*bh;
    float en = (tlx < brx && tly < bry) ? 1.0f : 0.0f;
    float ai = (brx - tlx)*(bry - tly)*en;
    return ai/(area_a + area_b - ai);
}

// K1: per-GT metadata + accumulator zeroing (replaces both memsets)
__global__ void k_pergt(const float* __restrict__ targets,
                        const float* __restrict__ masked_anchors,
                        const float* __restrict__ ref_anchors,
                        const int* __restrict__ anchor_mask,
                        float* __restrict__ gt_box, float* __restrict__ gt_delta,
                        float* __restrict__ gt_scale, int4* __restrict__ gt_meta,
                        int* __restrict__ nobj,
                        double* __restrict__ acc, double* __restrict__ acc_cond,
                        int* __restrict__ posflag){
    int t = blockIdx.x*blockDim.x + threadIdx.x;
    if (t >= BB*MM) return;
    if (t == 0) acc[0] = 0.0;
    if (t < BB){ acc_cond[t] = 0.0; posflag[t] = 0; }
    int b = t / MM, m = t % MM;
    int no = 0;
    for (int j = 0; j < MM; ++j){
        const float* r = targets + ((size_t)b*MM + j)*5;
        float s = r[0]+r[1]+r[2]+r[3]+r[4];
        no += (s > 0.0f) ? 1 : 0;
    }
    if (m == 0) nobj[b] = no;
    const float* g = targets + ((size_t)b*MM + m)*5;
    float gx = g[0]*(float)WW, gy = g[1]*(float)HH, gw = g[2]*(float)WW, gh = g[3]*(float)HH;
    int cls = (int)g[4];
    cls = min(max(cls, 0), NUM_CLASSES-1);
    bool valid = (m < no);
    int cx = (int)floorf(gx), cy = (int)floorf(gy);
    int cell = min(max(cy*WW + cx, 0), HW-1);
    float xg = (float)(cell % WW), yg = (float)(cell / WW);
    // argmax over 9 reference anchors at this cell (first max wins, like jnp.argmax)
    float best = -1e30f; int aidx = 0;
    for (int r = 0; r < 9; ++r){
        float off = (r % 3 == 0) ? 0.5f : 0.0f;   // ref_grid.at[:, 0::3, :2].add(0.5)
        float iou = iou_cxcywh_(xg+off, yg+off, ref_anchors[2*r], ref_anchors[2*r+1],
                                gx, gy, gw, gh);
        if (iou > best){ best = iou; aidx = r; }
    }
    bool dof = valid && (aidx == anchor_mask[0] || aidx == anchor_mask[1] || aidx == anchor_mask[2]);
    int a3 = aidx % 3;
    float mw = masked_anchors[2*a3], mh = masked_anchors[2*a3+1];
    gt_box[t*4+0] = gx; gt_box[t*4+1] = gy; gt_box[t*4+2] = gw; gt_box[t*4+3] = gh;
    gt_delta[t*4+0] = gx - xg; gt_delta[t*4+1] = gy - yg;
    gt_delta[t*4+2] = gw/mw;   gt_delta[t*4+3] = gh/mh;
    gt_scale[t] = sqrtf(2.0f - gw*gh/(float)WW/(float)HH);
    gt_meta[t] = make_int4(dof ? 1 : 0, cell, a3, cls);
}

// K2 (fused): max_iou + winner-by-scan + full loss.
// Conditional conf term (mi>=0.7, win<0) goes to acc_cond[b]; added in k_final iff posflag[b]==0.
__global__ void __launch_bounds__(256) k_fused(
        const float* __restrict__ outputs,
        const float* __restrict__ masked_anchors,
        const float* __restrict__ gt_box,
        const float* __restrict__ gt_delta,
        const float* __restrict__ gt_scale,
        const int4* __restrict__ gt_meta,
        const int* __restrict__ nobj,
        double* __restrict__ acc, double* __restrict__ acc_cond,
        int* __restrict__ posflag){
    __shared__ float s_box[MM][4];
    __shared__ float s_delta[MM][4];
    __shared__ float s_scale[MM];
    __shared__ int4  s_meta[MM];
    __shared__ double sred[256];
    __shared__ int s_any;

    int tid = threadIdx.x;
    int ba = blockIdx.y;
    int b = ba / AA, a = ba % AA;
    int hw = blockIdx.x*256 + tid;

    if (tid == 0) s_any = 0;
    if (tid < MM){
        int gi = b*MM + tid;
        s_box[tid][0] = gt_box[gi*4+0]; s_box[tid][1] = gt_box[gi*4+1];
        s_box[tid][2] = gt_box[gi*4+2]; s_box[tid][3] = gt_box[gi*4+3];
        s_delta[tid][0] = gt_delta[gi*4+0]; s_delta[tid][1] = gt_delta[gi*4+1];
        s_delta[tid][2] = gt_delta[gi*4+2]; s_delta[tid][3] = gt_delta[gi*4+3];
        s_scale[tid] = gt_scale[gi];
        s_meta[tid] = gt_meta[gi];
    }
    __syncthreads();

    int no = nobj[b];
    bool active = (hw < HW);
    double l = 0.0, lc = 0.0;
    bool pos = false;

    if (active && no > 0){
        int xg = hw % WW, yg = hw / WW;
        size_t base = ((size_t)b*CH + a*(5+NUM_CLASSES))*HW + hw;
        float o0 = outputs[base];
        float o1 = outputs[base + HW];
        float o2 = outputs[base + 2*HW];
        float o3 = outputs[base + 3*HW];
        float o4 = outputs[base + 4*HW];
        float bx = sigmoidf_(o0) + (float)xg;
        float by = sigmoidf_(o1) + (float)yg;
        float bw = expf(o2) * masked_anchors[2*a];
        float bh = expf(o3) * masked_anchors[2*a+1];

        float mi = -1.0f;
        for (int m = 0; m < no; ++m){
            float iou = iou_cxcywh_(bx, by, bw, bh,
                                    s_box[m][0], s_box[m][1], s_box[m][2], s_box[m][3]);
            mi = fmaxf(mi, iou);
        }
        pos = (mi > 0.7f);

        // winner = last (max m) matching GT; class bits = OR over all matching GTs
        int win = -1;
        unsigned long long cm0 = 0ull, cm1 = 0ull;
        for (int m = 0; m < MM; ++m){
            int4 mm = s_meta[m];
            if (mm.x && mm.y == hw && mm.z == a){
                win = m;
                int c = mm.w;
                if (c < 64) cm0 |= (1ull << c); else cm1 |= (1ull << (c-64));
            }
        }

        if (win >= 0){
            // conf BCE with target = max_iou (iou_mask forced 1 here)
            l += bce_(sigmoidf_(o4), mi);
            // box terms
            float dx = s_delta[win][0], dy = s_delta[win][1];
            float dw = s_delta[win][2], dh = s_delta[win][3];
            float s = s_scale[win];
            double w2 = (double)(s*s);
            l += bce_(sigmoidf_(o0), dx)*w2 + bce_(sigmoidf_(o1), dy)*w2;
            float e2 = expf(o2), e3 = expf(o3);
            float d2 = e2*s - dw*s, d3 = e3*s - dh*s;
            l += 0.5*((double)(d2*d2) + (double)(d3*d3));
            // class BCE over 80 classes
            for (int c = 0; c < NUM_CLASSES; ++c){
                float p = sigmoidf_(outputs[base + (size_t)(5+c)*HW]);
                float tt = (((c < 64 ? (cm0 >> c) : (cm1 >> (c-64))) & 1ull) != 0ull) ? 1.0f : 0.0f;
                l += bce_(p, tt);
            }
        } else {
            double v = bce_(sigmoidf_(o4), 0.0f);
            if (mi >= 0.7f) lc += v;   // kept only if npos[b]==0
            else            l  += v;
        }
    }

    if (pos) atomicOr(&s_any, 1);

    // reduce l
    sred[tid] = l;
    __syncthreads();
    for (int s = 128; s > 0; s >>= 1){
        if (tid < s) sred[tid] += sred[tid + s];
        __syncthreads();
    }
    if (tid == 0 && sred[0] != 0.0) atomicAdd(acc, sred[0]);
    __syncthreads();
    // reduce lc (rare)
    sred[tid] = lc;
    __syncthreads();
    for (int s = 128; s > 0; s >>= 1){
        if (tid < s) sred[tid] += sred[tid + s];
        __syncthreads();
    }
    if (tid == 0){
        if (sred[0] != 0.0) atomicAdd(&acc_cond[b], sred[0]);
        if (s_any) atomicOr(&posflag[b], 1);
    }
}

__global__ void k_final(const double* __restrict__ acc,
                        const double* __restrict__ acc_cond,
                        const int* __restrict__ posflag,
                        float* __restrict__ out){
    double s = acc[0];
    for (int b = 0; b < BB; ++b)
        if (posflag[b] == 0) s += acc_cond[b];
    out[0] = (float)s;
}

extern "C" void kernel_launch(void* const* d_in, const int* in_sizes, int n_in,
                              void* d_out, int out_size, void* d_ws, size_t ws_size,
                              hipStream_t stream) {
    const float* outputs        = (const float*)d_in[0];
    const float* targets        = (const float*)d_in[1];
    const float* masked_anchors = (const float*)d_in[2];
    const float* ref_anchors    = (const float*)d_in[3];
    const int*   anchor_mask    = (const int*)d_in[4];

    char* ws = (char*)d_ws;
    double* acc      = (double*)(ws + 0);       // 8 B
    double* acc_cond = (double*)(ws + 16);      // 128 B
    int*    posflag  = (int*)(ws + 144);        // 64 B
    int*    nobj     = (int*)(ws + 208);        // 64 B
    float*  gt_box   = (float*)(ws + 272);      // 12800 B
    float*  gt_delta = (float*)(ws + 13072);    // 12800 B
    float*  gt_scale = (float*)(ws + 25872);    // 3200 B
    int4*   gt_meta  = (int4*)(ws + 29072);     // 12800 B (end 41872)

    k_pergt<<<(BB*MM + 63)/64, 64, 0, stream>>>(targets, masked_anchors, ref_anchors,
                                                anchor_mask, gt_box, gt_delta, gt_scale,
                                                gt_meta, nobj, acc, acc_cond, posflag);
    dim3 grid((HW + 255)/256, BB*AA);
    k_fused<<<grid, 256, 0, stream>>>(outputs, masked_anchors, gt_box, gt_delta,
                                      gt_scale, gt_meta, nobj, acc, acc_cond, posflag);
    k_final<<<1, 1, 0, stream>>>(acc, acc_cond, posflag, (float*)d_out);
}

// Round 3
// 24.226 us; speedup vs baseline: 2.1028x; 1.4742x over previous
//
#include <hip/hip_runtime.h>
#include <math.h>

#define NUM_CLASSES 80
#define BB 16
#define AA 3
#define HH 85
#define WW 85
#define HW (HH*WW)
#define MM 50
#define CH (AA*(5+NUM_CLASSES))   // 255
#define BX ((HW + 255)/256)       // 29 blocks along hw
#define NB (BX*BB*AA)             // 1392 total blocks

__device__ __forceinline__ float sigmoidf_(float x){ return 1.0f/(1.0f+expf(-x)); }

__device__ __forceinline__ double bce_(float p, float t){
    float lp = logf(fmaxf(p, 1e-30f));
    float lq = logf(fmaxf(1.0f - p, 1e-30f));
    return -(double)(t*lp + (1.0f - t)*lq);
}

__device__ __forceinline__ float iou_cxcywh_(float ax,float ay,float aw,float ah,
                                             float bx,float by,float bw,float bh){
    float tlx = fmaxf(ax - aw*0.5f, bx - bw*0.5f);
    float tly = fmaxf(ay - ah*0.5f, by - bh*0.5f);
    float brx = fminf(ax + aw*0.5f, bx + bw*0.5f);
    float bry = fminf(ay + ah*0.5f, by + bh*0.5f);
    float area_a = aw*ah, area_b = bw*bh;
    float en = (tlx < brx && tly < bry) ? 1.0f : 0.0f;
    float ai = (brx - tlx)*(bry - tly)*en;
    return ai/(area_a + area_b - ai);
}

// ONE main kernel: per-block GT metadata (redundant, cheap) + LDS winner scatter + loss.
// Per-block partials to distinct slots -> no global atomics, fully deterministic.
__global__ void __launch_bounds__(256) k_main(
        const float* __restrict__ outputs,
        const float* __restrict__ targets,
        const float* __restrict__ masked_anchors,
        const float* __restrict__ ref_anchors,
        const int* __restrict__ anchor_mask,
        double* __restrict__ part_l,
        double* __restrict__ part_lc,
        int* __restrict__ part_pos){
    __shared__ float s_box[MM][4];
    __shared__ float s_delta[MM][4];
    __shared__ float s_scale[MM];
    __shared__ int   s_flag[MM];
    __shared__ int   s_no;
    __shared__ int   s_win[256];
    __shared__ unsigned int s_cm[256][3];
    __shared__ double sred[256];
    __shared__ int s_any;

    int tid = threadIdx.x;
    int ba  = blockIdx.y;            // b*AA + a
    int b = ba / AA, a = ba % AA;
    int base = blockIdx.x * 256;
    int bid = ba * BX + blockIdx.x;  // flat block id

    s_win[tid] = -1;
    s_cm[tid][0] = 0u; s_cm[tid][1] = 0u; s_cm[tid][2] = 0u;
    if (tid == 0) s_any = 0;

    // ---- phase A: per-GT metadata for batch b (threads 0..MM-1) ----
    float g0=0.f,g1=0.f,g2=0.f,g3=0.f,g4=0.f;
    if (tid < MM){
        const float* g = targets + ((size_t)b*MM + tid)*5;
        g0=g[0]; g1=g[1]; g2=g[2]; g3=g[3]; g4=g[4];
        s_flag[tid] = (g0+g1+g2+g3+g4 > 0.0f) ? 1 : 0;
    }
    __syncthreads();
    if (tid == 0){
        int n = 0;
        for (int j = 0; j < MM; ++j) n += s_flag[j];
        s_no = n;
    }
    __syncthreads();
    int no = s_no;
    if (tid < MM){
        float gx = g0*(float)WW, gy = g1*(float)HH, gw = g2*(float)WW, gh = g3*(float)HH;
        int cls = min(max((int)g4, 0), NUM_CLASSES-1);
        bool valid = (tid < no);
        int cx = (int)floorf(gx), cy = (int)floorf(gy);
        int cell = min(max(cy*WW + cx, 0), HW-1);
        float xg = (float)(cell % WW), yg = (float)(cell / WW);
        float bestv = -1e30f; int aidx = 0;
        for (int r = 0; r < 9; ++r){
            float off = (r % 3 == 0) ? 0.5f : 0.0f;  // ref_grid.at[:, 0::3, :2].add(0.5)
            float iou = iou_cxcywh_(xg+off, yg+off, ref_anchors[2*r], ref_anchors[2*r+1],
                                    gx, gy, gw, gh);
            if (iou > bestv){ bestv = iou; aidx = r; }   // first-max wins (jnp.argmax)
        }
        bool dof = valid && (aidx == anchor_mask[0] || aidx == anchor_mask[1] || aidx == anchor_mask[2]);
        int a3 = aidx % 3;
        float mw = masked_anchors[2*a3], mh = masked_anchors[2*a3+1];
        s_box[tid][0] = gx; s_box[tid][1] = gy; s_box[tid][2] = gw; s_box[tid][3] = gh;
        s_delta[tid][0] = gx - xg; s_delta[tid][1] = gy - yg;
        s_delta[tid][2] = gw/mw;   s_delta[tid][3] = gh/mh;
        s_scale[tid] = sqrtf(2.0f - gw*gh/(float)WW/(float)HH);
        if (dof && a3 == a){
            int ci = cell - base;
            if (ci >= 0 && ci < 256){
                atomicMax(&s_win[ci], tid);                       // last-m-wins (scan overwrite)
                atomicOr(&s_cm[ci][cls >> 5], 1u << (cls & 31));  // OR of one-hots
            }
        }
    }
    __syncthreads();

    // ---- phase B: per-cell loss ----
    int hw = base + tid;
    double l = 0.0, lc = 0.0;
    bool pos = false;
    if (hw < HW && no > 0){
        int xg = hw % WW, yg = hw / WW;
        size_t obase = ((size_t)b*CH + a*(5+NUM_CLASSES))*HW + hw;
        float o0 = outputs[obase];
        float o1 = outputs[obase + HW];
        float o2 = outputs[obase + 2*HW];
        float o3 = outputs[obase + 3*HW];
        float o4 = outputs[obase + 4*HW];
        float bx = sigmoidf_(o0) + (float)xg;
        float by = sigmoidf_(o1) + (float)yg;
        float bw = expf(o2) * masked_anchors[2*a];
        float bh = expf(o3) * masked_anchors[2*a+1];

        float mi = -1.0f;
        for (int m = 0; m < no; ++m)
            mi = fmaxf(mi, iou_cxcywh_(bx, by, bw, bh,
                                       s_box[m][0], s_box[m][1], s_box[m][2], s_box[m][3]));
        pos = (mi > 0.7f);

        int win = s_win[tid];
        if (win >= 0){
            l += bce_(sigmoidf_(o4), mi);          // iou_mask forced 1 at winner cells
            float dx = s_delta[win][0], dy = s_delta[win][1];
            float dw = s_delta[win][2], dh = s_delta[win][3];
            float s = s_scale[win];
            double w2 = (double)(s*s);
            l += bce_(sigmoidf_(o0), dx)*w2 + bce_(sigmoidf_(o1), dy)*w2;
            float d2 = expf(o2)*s - dw*s, d3 = expf(o3)*s - dh*s;
            l += 0.5*((double)(d2*d2) + (double)(d3*d3));
            unsigned int c0 = s_cm[tid][0], c1 = s_cm[tid][1], c2 = s_cm[tid][2];
            for (int c = 0; c < NUM_CLASSES; ++c){
                float p = sigmoidf_(outputs[obase + (size_t)(5+c)*HW]);
                unsigned int w = (c < 32) ? c0 : ((c < 64) ? c1 : c2);
                float tt = ((w >> (c & 31)) & 1u) ? 1.0f : 0.0f;
                l += bce_(p, tt);
            }
        } else {
            double v = bce_(sigmoidf_(o4), 0.0f);
            if (mi >= 0.7f) lc += v;               // kept only if npos[b]==0 (resolved in k_final)
            else            l  += v;
        }
    }
    if (pos) atomicOr(&s_any, 1);

    // block reduce l
    sred[tid] = l;
    __syncthreads();
    for (int s = 128; s > 0; s >>= 1){
        if (tid < s) sred[tid] += sred[tid + s];
        __syncthreads();
    }
    if (tid == 0) part_l[bid] = sred[0];
    __syncthreads();
    // block reduce lc
    sred[tid] = lc;
    __syncthreads();
    for (int s = 128; s > 0; s >>= 1){
        if (tid < s) sred[tid] += sred[tid + s];
        __syncthreads();
    }
    if (tid == 0){
        part_lc[bid] = sred[0];
        part_pos[bid] = s_any;
    }
}

__global__ void __launch_bounds__(256) k_final(
        const double* __restrict__ part_l,
        const double* __restrict__ part_lc,
        const int* __restrict__ part_pos,
        float* __restrict__ out){
    __shared__ int s_posb[BB];
    __shared__ double sred[256];
    int tid = threadIdx.x;
    if (tid < BB){
        int p = 0;
        for (int a = 0; a < AA; ++a)
            for (int x = 0; x < BX; ++x)
                p |= part_pos[(tid*AA + a)*BX + x];
        s_posb[tid] = p;
    }
    __syncthreads();
    double sum = 0.0;
    for (int i = tid; i < NB; i += 256){
        sum += part_l[i];
        int b = i / (AA*BX);
        if (s_posb[b] == 0) sum += part_lc[i];
    }
    sred[tid] = sum;
    __syncthreads();
    for (int s = 128; s > 0; s >>= 1){
        if (tid < s) sred[tid] += sred[tid + s];
        __syncthreads();
    }
    if (tid == 0) out[0] = (float)sred[0];
}

extern "C" void kernel_launch(void* const* d_in, const int* in_sizes, int n_in,
                              void* d_out, int out_size, void* d_ws, size_t ws_size,
                              hipStream_t stream) {
    const float* outputs        = (const float*)d_in[0];
    const float* targets        = (const float*)d_in[1];
    const float* masked_anchors = (const float*)d_in[2];
    const float* ref_anchors    = (const float*)d_in[3];
    const int*   anchor_mask    = (const int*)d_in[4];

    char* ws = (char*)d_ws;
    double* part_l   = (double*)(ws + 0);          // 11136 B
    double* part_lc  = (double*)(ws + 11136);      // 11136 B
    int*    part_pos = (int*)(ws + 22272);         // 5568 B (end 27840)

    dim3 grid(BX, BB*AA);
    k_main<<<grid, 256, 0, stream>>>(outputs, targets, masked_anchors, ref_anchors,
                                     anchor_mask, part_l, part_lc, part_pos);
    k_final<<<1, 256, 0, stream>>>(part_l, part_lc, part_pos, (float*)d_out);
}